// Round 10
// baseline (219.937 us; speedup 1.0000x reference)
//
#include <hip/hip_runtime.h>
#include <math.h>

#define D 4096
#define K 128
#define KP 129          // K+1 (augmented sqrt(EPS)*ones column)
#define NC 144          // padded col count for VbT / Yb (9 tiles of 16; cols >= 129 zero)
#define NROWS 8192
#define QS 144          // Q row stride
#define MS 132          // M row stride
#define NP 132          // padded order for chol
#define NPS 136         // LDS row stride (float4-aligned)
#define NB 12           // panel width (11 panels)
#define NPAN (NP / NB)
#define LOG2PI 1.8378770664093453

typedef __attribute__((ext_vector_type(8))) short bh8;     // 8 bf16 (4 VGPRs)
typedef __attribute__((ext_vector_type(4))) float f32x4;   // MFMA acc

// ---------------- helpers ----------------
__device__ __forceinline__ unsigned short f2bf(float f) {  // RNE
  unsigned int u = __float_as_uint(f);
  unsigned int r = u + 0x7FFFu + ((u >> 16) & 1u);
  return (unsigned short)(r >> 16);
}
__device__ __forceinline__ float bf2f(unsigned short u) {
  return __uint_as_float(((unsigned int)u) << 16);
}
__device__ __forceinline__ float blo(unsigned int v) { return __uint_as_float(v << 16); }
__device__ __forceinline__ float bhi(unsigned int v) { return __uint_as_float(v & 0xFFFF0000u); }

__device__ __forceinline__ float blockReduceSum256(float v) {
  #pragma unroll
  for (int off = 32; off > 0; off >>= 1) v += __shfl_down(v, off, 64);
  __shared__ float tmp[4];
  __syncthreads();
  if ((threadIdx.x & 63) == 0) tmp[threadIdx.x >> 6] = v;
  __syncthreads();
  float r = 0.0f;
  if (threadIdx.x == 0) r = tmp[0] + tmp[1] + tmp[2] + tmp[3];
  return r;                              // valid on tid 0 only
}

// ---------------- VbT[c][d] = bf16( U[d][c] / sigma[d] ), rows c>=129 zero ----------------
__global__ __launch_bounds__(256) void k_prep(const float* __restrict__ theta,
                                              unsigned short* __restrict__ VbT) {
  int c = blockIdx.x;                    // 0..143
  const float* sg = theta + (size_t)D * K + D;
  float al = (c < K) ? theta[(size_t)D * K + 2 * D + c] : 0.0f;
  for (int d = threadIdx.x; d < D; d += 256) {
    float v;
    if (c < K)       v = theta[(size_t)d * K + c] * al / sg[d];
    else if (c == K) v = 1.0e-3f / sg[d];
    else             v = 0.0f;
    VbT[(size_t)c * D + d] = f2bf(v);
  }
}

// ---------------- M = I + sum_d sigma_d VbT[j][d] VbT[k][d] ----------------
__global__ __launch_bounds__(256) void k_M(const float* __restrict__ theta,
                                           const unsigned short* __restrict__ VbT,
                                           float* __restrict__ M) {
  int j = blockIdx.x, kk2 = blockIdx.y;
  if (kk2 < j) return;                   // symmetry
  const float* sg = theta + (size_t)D * K + D;
  float acc = 0.0f;
  for (int d0 = threadIdx.x * 8; d0 < D; d0 += 2048) {
    uint4 ua = *reinterpret_cast<const uint4*>(&VbT[(size_t)j * D + d0]);
    uint4 ub = *reinterpret_cast<const uint4*>(&VbT[(size_t)kk2 * D + d0]);
    float4 s0 = *reinterpret_cast<const float4*>(&sg[d0]);
    float4 s1 = *reinterpret_cast<const float4*>(&sg[d0 + 4]);
    acc += s0.x * blo(ua.x) * blo(ub.x) + s0.y * bhi(ua.x) * bhi(ub.x)
         + s0.z * blo(ua.y) * blo(ub.y) + s0.w * bhi(ua.y) * bhi(ub.y)
         + s1.x * blo(ua.z) * blo(ub.z) + s1.y * bhi(ua.z) * bhi(ub.z)
         + s1.z * blo(ua.w) * blo(ub.w) + s1.w * bhi(ua.w) * bhi(ub.w);
  }
  float r = blockReduceSum256(acc);
  if (threadIdx.x == 0) {
    float m = r + (j == kk2 ? 1.0f : 0.0f);
    M[j * MS + kk2] = m;
    M[kk2 * MS + j] = m;
  }
}

// ---------------- fused: tvec (b<KP), mvec (KP<=b<2KP), scalars (b==2KP) ----------------
__global__ __launch_bounds__(256) void k_small(const float* __restrict__ theta,
                                               const unsigned short* __restrict__ VbT,
                                               const float* __restrict__ colsum,
                                               const float* __restrict__ colsumsq,
                                               float* __restrict__ tvec,
                                               float* __restrict__ mvec,
                                               float* __restrict__ scalars) {
  int b = blockIdx.x;
  if (b < 2 * KP) {
    int c = (b >= KP) ? b - KP : b;
    const float* src = (b >= KP) ? (theta + (size_t)D * K) : colsum;
    float a = 0.0f;
    for (int d = threadIdx.x; d < D; d += 256) a += bf2f(VbT[(size_t)c * D + d]) * src[d];
    float r = blockReduceSum256(a);
    if (threadIdx.x == 0) { if (b < KP) tvec[c] = r; else mvec[c] = r; }
  } else {
    const float* mu = theta + (size_t)D * K;
    const float* sg = theta + (size_t)D * K + D;
    float a = 0.0f, bb = 0.0f;
    for (int d = threadIdx.x; d < D; d += 256) {
      float s = sg[d];
      float m = mu[d];
      a += logf(s);
      bb += (colsumsq[d] - 2.0f * m * colsum[d] + (float)NROWS * m * m) / s;
    }
    float ra = blockReduceSum256(a);
    float rb = blockReduceSum256(bb);
    if (threadIdx.x == 0) { scalars[0] = ra; scalars[1] = rb; }
  }
}

// ================= fused parallel kernel: chol (block 0) | gemm (1..256) | colstats =================
#define GBM 32
#define GBK 128
#define NSTEP (D / GBK)     // 32
#define XSS 136             // LDS row stride in shorts
#define GEMM_BLOCKS (NROWS / GBM)   // 256
#define CS_BLOCKS 32
#define CS_ROWS (NROWS / CS_BLOCKS) // 256

struct CholSh {
  float A[NP][NPS];
  float G[NP][NPS];
};
struct GemmSh {
  unsigned short Xs[GBM][XSS];
  unsigned short Vs[NC][XSS];
};
union ParSh {
  CholSh c;
  GemmSh g;
};

__device__ void chol_body(CholSh& sh, const float* __restrict__ Mg,
                          float* __restrict__ Gg, float* __restrict__ scalars) {
  auto& A = sh.A;
  auto& G = sh.G;
  __shared__ float redB[16];
  int tid = threadIdx.x;

  if (tid == 0) scalars[3] = 0.0f;       // trace accumulator for k_trace
  for (int idx = tid; idx < NP * NP; idx += 1024) {
    int r = idx / NP, c = idx - r * NP;
    A[r][c] = (r < KP && c < KP) ? Mg[r * MS + c] : (r == c ? 1.0f : 0.0f);
  }
  __syncthreads();

  // ---- blocked Cholesky with fused triangular inverse ----
  // After panel p: columns 0..p of L are final, G row-blocks 0..p complete.
  for (int p = 0; p < NPAN; ++p) {
    int j0 = p * NB, j1 = j0 + NB;
    int nbrows = NP - j1;
    // phase 1: diag chol + inverse (registers, waves 0/1 redundant) + panel solve
    if (tid < 128) {
      float T[NB][NB];
      #pragma unroll
      for (int r = 0; r < NB; ++r)
        #pragma unroll
        for (int c = 0; c <= r; ++c)
          T[r][c] = A[j0 + r][j0 + c];
      float dinv[NB];
      #pragma unroll
      for (int jj = 0; jj < NB; ++jj) {
        float dv = sqrtf(T[jj][jj]);
        float iv = 1.0f / dv;
        dinv[jj] = iv;
        #pragma unroll
        for (int r = jj + 1; r < NB; ++r) T[r][jj] *= iv;
        #pragma unroll
        for (int cc = jj + 1; cc < NB; ++cc)
          #pragma unroll
          for (int r = cc; r < NB; ++r)
            T[r][cc] -= T[r][jj] * T[cc][jj];
      }
      #pragma unroll
      for (int r = 0; r < NB; ++r) {     // in-place row-wise inverse -> G_pp
        float tmp[NB];
        #pragma unroll
        for (int c = 0; c < r; ++c) {
          float s = 0.0f;
          #pragma unroll
          for (int k = c; k < r; ++k) s += T[r][k] * T[k][c];
          tmp[c] = -s * dinv[r];
        }
        #pragma unroll
        for (int c = 0; c < r; ++c) T[r][c] = tmp[c];
        T[r][r] = dinv[r];
      }
      if (tid == 0) {                    // stash G_pp (upper zeros)
        #pragma unroll
        for (int r = 0; r < NB; ++r) {
          float g[NB];
          #pragma unroll
          for (int c = 0; c < NB; ++c) g[c] = (c <= r) ? T[r][c] : 0.0f;
          float4* dst = reinterpret_cast<float4*>(&G[j0 + r][j0]);
          float4 g0 = {g[0], g[1], g[2], g[3]};
          float4 g1 = {g[4], g[5], g[6], g[7]};
          float4 g2 = {g[8], g[9], g[10], g[11]};
          dst[0] = g0; dst[1] = g1; dst[2] = g2;
        }
      }
      if (tid < nbrows) {                // fused panel solve, G_pp from registers
        int r = j1 + tid;
        float* arow = &A[r][j0];
        float4 q0 = *reinterpret_cast<const float4*>(arow);
        float4 q1 = *reinterpret_cast<const float4*>(arow + 4);
        float4 q2 = *reinterpret_cast<const float4*>(arow + 8);
        float ro[NB] = {q0.x, q0.y, q0.z, q0.w, q1.x, q1.y, q1.z, q1.w,
                        q2.x, q2.y, q2.z, q2.w};
        float rn[NB];
        #pragma unroll
        for (int cc = 0; cc < NB; ++cc) {
          float s = 0.0f;
          #pragma unroll
          for (int k = 0; k <= cc; ++k) s += ro[k] * T[cc][k];
          rn[cc] = s;
        }
        float4 w0 = {rn[0], rn[1], rn[2], rn[3]};
        float4 w1 = {rn[4], rn[5], rn[6], rn[7]};
        float4 w2 = {rn[8], rn[9], rn[10], rn[11]};
        *reinterpret_cast<float4*>(arow) = w0;
        *reinterpret_cast<float4*>(arow + 4) = w1;
        *reinterpret_cast<float4*>(arow + 8) = w2;
      }
    }
    __syncthreads();
    // phase 2: {G row-block p for q<p} on threads 0..p*12, + trailing update (all)
    if (tid < p * NB) {
      int q = tid / NB, j = tid - (tid / NB) * NB;
      int qI = q * NB;
      float T2[NB] = {0, 0, 0, 0, 0, 0, 0, 0, 0, 0, 0, 0};
      for (int k = q; k < p; ++k) {
        int kI = k * NB;
        #pragma unroll
        for (int n = 0; n < NB; ++n) {
          float g = G[kI + n][qI + j];
          #pragma unroll
          for (int m = 0; m < NB; ++m) T2[m] += A[j0 + m][kI + n] * g;
        }
      }
      #pragma unroll
      for (int i = 0; i < NB; ++i) {
        float s = 0.0f;
        #pragma unroll
        for (int m = 0; m <= i; ++m) s += G[j0 + i][j0 + m] * T2[m];
        G[j0 + i][qI + j] = -s;
      }
    }
    // trailing rank-12 update, lower tasks only, register-staged operands
    int nt = nbrows / 4;
    int ntasks = nt * (nt + 1) / 2;
    for (int t = tid; t < ntasks; t += 1024) {
      int r4 = (int)((sqrtf(8.0f * (float)t + 1.0f) - 1.0f) * 0.5f);
      while ((r4 + 1) * (r4 + 2) / 2 <= t) ++r4;
      while (r4 * (r4 + 1) / 2 > t) --r4;
      int c4 = t - r4 * (r4 + 1) / 2;
      int r = j1 + r4 * 4, c = j1 + c4 * 4;
      float pr[4][NB], pc[4][NB];
      #pragma unroll
      for (int i = 0; i < 4; ++i) {
        float4 a0 = *reinterpret_cast<const float4*>(&A[r + i][j0]);
        float4 a1 = *reinterpret_cast<const float4*>(&A[r + i][j0 + 4]);
        float4 a2 = *reinterpret_cast<const float4*>(&A[r + i][j0 + 8]);
        pr[i][0] = a0.x; pr[i][1] = a0.y; pr[i][2] = a0.z; pr[i][3] = a0.w;
        pr[i][4] = a1.x; pr[i][5] = a1.y; pr[i][6] = a1.z; pr[i][7] = a1.w;
        pr[i][8] = a2.x; pr[i][9] = a2.y; pr[i][10] = a2.z; pr[i][11] = a2.w;
        float4 b0 = *reinterpret_cast<const float4*>(&A[c + i][j0]);
        float4 b1 = *reinterpret_cast<const float4*>(&A[c + i][j0 + 4]);
        float4 b2 = *reinterpret_cast<const float4*>(&A[c + i][j0 + 8]);
        pc[i][0] = b0.x; pc[i][1] = b0.y; pc[i][2] = b0.z; pc[i][3] = b0.w;
        pc[i][4] = b1.x; pc[i][5] = b1.y; pc[i][6] = b1.z; pc[i][7] = b1.w;
        pc[i][8] = b2.x; pc[i][9] = b2.y; pc[i][10] = b2.z; pc[i][11] = b2.w;
      }
      float4 av[4];
      #pragma unroll
      for (int i = 0; i < 4; ++i)
        av[i] = *reinterpret_cast<const float4*>(&A[r + i][c]);
      #pragma unroll
      for (int k = 0; k < NB; ++k) {
        #pragma unroll
        for (int i = 0; i < 4; ++i) {
          av[i].x -= pr[i][k] * pc[0][k];
          av[i].y -= pr[i][k] * pc[1][k];
          av[i].z -= pr[i][k] * pc[2][k];
          av[i].w -= pr[i][k] * pc[3][k];
        }
      }
      #pragma unroll
      for (int i = 0; i < 4; ++i)
        *reinterpret_cast<float4*>(&A[r + i][c]) = av[i];
    }
    __syncthreads();
  }

  // ---- write G to global ----
  for (int idx = tid; idx < NP * NP; idx += 1024) {
    int r = idx / NP, c = idx - r * NP;
    Gg[idx] = G[r][c];
  }

  // ---- logdet from diag(G) = 1/diag(L) ----
  float lg = (tid < NP) ? logf(G[tid][tid]) : 0.0f;
  #pragma unroll
  for (int off = 32; off > 0; off >>= 1) lg += __shfl_down(lg, off, 64);
  __syncthreads();
  if ((tid & 63) == 0) redB[tid >> 6] = lg;
  __syncthreads();
  if (tid == 0) {
    float sgl = 0.0f;
    #pragma unroll
    for (int i = 0; i < 16; ++i) sgl += redB[i];
    scalars[2] = -2.0f * sgl;            // logdet(M)
  }
}

__device__ void gemm_body(GemmSh& sh, const float* __restrict__ x,
                          const unsigned short* __restrict__ VbT,
                          unsigned short* __restrict__ Yb, int blk) {
  auto& Xs = sh.Xs;
  auto& Vs = sh.Vs;
  int tid = threadIdx.x;                 // < 512
  int row0 = blk * GBM;
  int wid = tid >> 6, lane = tid & 63;
  int lr = lane & 15, lk = (lane >> 4) * 8;
  int rt = wid & 1;
  int cg = wid >> 1;
  int ct0 = (cg == 0) ? 0 : (cg * 2 + 1);
  int nct = (cg == 0) ? 3 : 2;

  int sxr = tid >> 4;
  int sxk = (tid & 15) * 8;
  int vrb = tid >> 4;
  int vk  = (tid & 15) * 8;

  float4 xr0, xr1;
  uint4 vr0, vr1, vr2, vr3, vr4;
  {
    const float* xb = &x[(size_t)(row0 + sxr) * D + sxk];
    xr0 = *reinterpret_cast<const float4*>(xb);
    xr1 = *reinterpret_cast<const float4*>(xb + 4);
    const unsigned short* vb = &VbT[(size_t)vrb * D + vk];
    vr0 = *reinterpret_cast<const uint4*>(vb);
    vr1 = *reinterpret_cast<const uint4*>(vb + (size_t)32 * D);
    vr2 = *reinterpret_cast<const uint4*>(vb + (size_t)64 * D);
    vr3 = *reinterpret_cast<const uint4*>(vb + (size_t)96 * D);
    if (tid < 256) vr4 = *reinterpret_cast<const uint4*>(vb + (size_t)128 * D);
  }

  f32x4 acc0 = {0, 0, 0, 0}, acc1 = {0, 0, 0, 0}, acc2 = {0, 0, 0, 0};

  for (int s = 0; s < NSTEP; ++s) {
    {
      uint4 w;
      w.x = (unsigned)f2bf(xr0.x) | ((unsigned)f2bf(xr0.y) << 16);
      w.y = (unsigned)f2bf(xr0.z) | ((unsigned)f2bf(xr0.w) << 16);
      w.z = (unsigned)f2bf(xr1.x) | ((unsigned)f2bf(xr1.y) << 16);
      w.w = (unsigned)f2bf(xr1.z) | ((unsigned)f2bf(xr1.w) << 16);
      *reinterpret_cast<uint4*>(&Xs[sxr][sxk]) = w;
      unsigned short* vd = &Vs[vrb][vk];
      *reinterpret_cast<uint4*>(vd) = vr0;
      *reinterpret_cast<uint4*>(vd + 32 * XSS) = vr1;
      *reinterpret_cast<uint4*>(vd + 64 * XSS) = vr2;
      *reinterpret_cast<uint4*>(vd + 96 * XSS) = vr3;
      if (tid < 256) *reinterpret_cast<uint4*>(vd + 128 * XSS) = vr4;
    }
    __syncthreads();
    if (s + 1 < NSTEP) {
      const float* xb = &x[(size_t)(row0 + sxr) * D + (s + 1) * GBK + sxk];
      xr0 = *reinterpret_cast<const float4*>(xb);
      xr1 = *reinterpret_cast<const float4*>(xb + 4);
      const unsigned short* vb = &VbT[(size_t)vrb * D + (s + 1) * GBK + vk];
      vr0 = *reinterpret_cast<const uint4*>(vb);
      vr1 = *reinterpret_cast<const uint4*>(vb + (size_t)32 * D);
      vr2 = *reinterpret_cast<const uint4*>(vb + (size_t)64 * D);
      vr3 = *reinterpret_cast<const uint4*>(vb + (size_t)96 * D);
      if (tid < 256) vr4 = *reinterpret_cast<const uint4*>(vb + (size_t)128 * D);
    }
    #pragma unroll
    for (int ks = 0; ks < 4; ++ks) {
      bh8 a = *reinterpret_cast<const bh8*>(&Xs[rt * 16 + lr][ks * 32 + lk]);
      bh8 b0 = *reinterpret_cast<const bh8*>(&Vs[ct0 * 16 + lr][ks * 32 + lk]);
      acc0 = __builtin_amdgcn_mfma_f32_16x16x32_bf16(a, b0, acc0, 0, 0, 0);
      bh8 b1 = *reinterpret_cast<const bh8*>(&Vs[(ct0 + 1) * 16 + lr][ks * 32 + lk]);
      acc1 = __builtin_amdgcn_mfma_f32_16x16x32_bf16(a, b1, acc1, 0, 0, 0);
      if (nct == 3) {
        bh8 b2 = *reinterpret_cast<const bh8*>(&Vs[(ct0 + 2) * 16 + lr][ks * 32 + lk]);
        acc2 = __builtin_amdgcn_mfma_f32_16x16x32_bf16(a, b2, acc2, 0, 0, 0);
      }
    }
    __syncthreads();
  }

  int rw = row0 + rt * 16 + ((lane >> 4) << 2);
  #pragma unroll
  for (int g = 0; g < 4; ++g)
    Yb[(size_t)(rw + g) * NC + ct0 * 16 + lr] = f2bf(acc0[g]);
  #pragma unroll
  for (int g = 0; g < 4; ++g)
    Yb[(size_t)(rw + g) * NC + (ct0 + 1) * 16 + lr] = f2bf(acc1[g]);
  if (nct == 3) {
    #pragma unroll
    for (int g = 0; g < 4; ++g)
      Yb[(size_t)(rw + g) * NC + (ct0 + 2) * 16 + lr] = f2bf(acc2[g]);
  }
}

__device__ void colstats_body(const float* __restrict__ x,
                              float* __restrict__ colsum,
                              float* __restrict__ colsumsq, int cb) {
  int d4 = threadIdx.x;                  // 0..1023 covers D/4
  int i0 = cb * CS_ROWS;
  float4 s1 = {0, 0, 0, 0}, s2 = {0, 0, 0, 0};
  for (int i = i0; i < i0 + CS_ROWS; ++i) {
    float4 v = *reinterpret_cast<const float4*>(&x[(size_t)i * D + d4 * 4]);
    s1.x += v.x; s1.y += v.y; s1.z += v.z; s1.w += v.w;
    s2.x += v.x * v.x; s2.y += v.y * v.y; s2.z += v.z * v.z; s2.w += v.w * v.w;
  }
  atomicAdd(&colsum[d4 * 4 + 0], s1.x); atomicAdd(&colsum[d4 * 4 + 1], s1.y);
  atomicAdd(&colsum[d4 * 4 + 2], s1.z); atomicAdd(&colsum[d4 * 4 + 3], s1.w);
  atomicAdd(&colsumsq[d4 * 4 + 0], s2.x); atomicAdd(&colsumsq[d4 * 4 + 1], s2.y);
  atomicAdd(&colsumsq[d4 * 4 + 2], s2.z); atomicAdd(&colsumsq[d4 * 4 + 3], s2.w);
}

__global__ __launch_bounds__(1024, 1) void k_par(const float* __restrict__ x,
                                                 const unsigned short* __restrict__ VbT,
                                                 unsigned short* __restrict__ Yb,
                                                 const float* __restrict__ Mg,
                                                 float* __restrict__ Gg,
                                                 float* __restrict__ scalars,
                                                 float* __restrict__ colsum,
                                                 float* __restrict__ colsumsq) {
  __shared__ ParSh sh;
  int b = blockIdx.x;
  if (b == 0) {
    chol_body(sh.c, Mg, Gg, scalars);
  } else if (b <= GEMM_BLOCKS) {
    if (threadIdx.x >= 512) return;      // exit before any barrier
    gemm_body(sh.g, x, VbT, Yb, b - 1);
  } else {
    colstats_body(x, colsum, colsumsq, b - 1 - GEMM_BLOCKS);
  }
}

// ---------------- Q += Yb^T Yb  (bf16 in, symmetry, row-split atomics) ----------------
#define SYRK_ZSPLIT 16
__global__ __launch_bounds__(256) void k_syrk(const unsigned short* __restrict__ Yb,
                                              float* __restrict__ Q) {
  int bj = blockIdx.x * 16, bk = blockIdx.y * 16;
  if (bk < bj) return;                   // symmetry
  __shared__ float Ya[64][17];
  __shared__ float Yc[64][17];
  int i0base = blockIdx.z * (NROWS / SYRK_ZSPLIT);
  int tid = threadIdx.x;
  int tj = tid & 15, tk = tid >> 4;
  int lr = tid >> 2, lc = (tid & 3) * 4;
  float acc = 0.0f;
  for (int i0 = i0base; i0 < i0base + NROWS / SYRK_ZSPLIT; i0 += 64) {
    ushort4 va = *reinterpret_cast<const ushort4*>(&Yb[(size_t)(i0 + lr) * NC + bj + lc]);
    ushort4 vc = *reinterpret_cast<const ushort4*>(&Yb[(size_t)(i0 + lr) * NC + bk + lc]);
    Ya[lr][lc + 0] = bf2f(va.x); Ya[lr][lc + 1] = bf2f(va.y);
    Ya[lr][lc + 2] = bf2f(va.z); Ya[lr][lc + 3] = bf2f(va.w);
    Yc[lr][lc + 0] = bf2f(vc.x); Yc[lr][lc + 1] = bf2f(vc.y);
    Yc[lr][lc + 2] = bf2f(vc.z); Yc[lr][lc + 3] = bf2f(vc.w);
    __syncthreads();
    #pragma unroll
    for (int ii = 0; ii < 64; ++ii) acc += Ya[ii][tj] * Yc[ii][tk];
    __syncthreads();
  }
  atomicAdd(&Q[(bj + tj) * QS + bk + tk], acc);
  if (bj != bk) atomicAdd(&Q[(bk + tk) * QS + bj + tj], acc);
}

// ---------------- k_trace: tr(M^-1 S) = sum_{j<=k} (2-d) H_jk S_jk, H = G^T G ----------------
__global__ __launch_bounds__(256) void k_trace(const float* __restrict__ Gg,
                                               const float* __restrict__ Qg,
                                               const float* __restrict__ tvec,
                                               const float* __restrict__ mvec,
                                               float* __restrict__ scalars) {
  int bj = blockIdx.x * 16, bk = blockIdx.y * 16;
  if (bk < bj) return;                   // upper tiles only
  int tj = threadIdx.x & 15, tk = threadIdx.x >> 4;
  int j = bj + tj, k = bk + tk;
  float acc = 0.0f;
  if (j <= k && k < NP) {
    float h0 = 0.f, h1 = 0.f;
    int i = k;
    for (; i + 1 < NP; i += 2) {
      h0 += Gg[(size_t)i * NP + j] * Gg[(size_t)i * NP + k];
      h1 += Gg[(size_t)(i + 1) * NP + j] * Gg[(size_t)(i + 1) * NP + k];
    }
    for (; i < NP; ++i) h0 += Gg[(size_t)i * NP + j] * Gg[(size_t)i * NP + k];
    float h = h0 + h1;
    float S = 0.0f;
    if (j < KP && k < KP) {
      float tlj = tvec[j], mlj = mvec[j], tlk = tvec[k], mlk = mvec[k];
      S = Qg[j * QS + k] - tlj * mlk - mlj * tlk + (float)NROWS * mlj * mlk;
    }
    acc = ((j == k) ? 1.0f : 2.0f) * h * S;
  }
  float r = blockReduceSum256(acc);
  if (threadIdx.x == 0) atomicAdd(&scalars[3], r);
}

// ---------------- k_combine ----------------
__global__ void k_combine(const float* __restrict__ scalars,
                          const int* __restrict__ fds,
                          float* __restrict__ out) {
  if (threadIdx.x == 0) {
    double sumlog  = (double)scalars[0];
    double term1   = (double)scalars[1];
    double logdetM = (double)scalars[2];
    double tr      = (double)scalars[3];
    double total = (double)NROWS * (double)D * LOG2PI
                 + (double)NROWS * (sumlog + logdetM)
                 + term1 - tr;
    double scale = (double)fds[0] / (double)NROWS;
    out[0] = (float)(scale * (-0.5) * total);
  }
}

// ---------------- launch ----------------
extern "C" void kernel_launch(void* const* d_in, const int* in_sizes, int n_in,
                              void* d_out, int out_size, void* d_ws, size_t ws_size,
                              hipStream_t stream) {
  const float* x     = (const float*)d_in[0];
  const float* theta = (const float*)d_in[1];
  const int*   fds   = (const int*)d_in[2];
  float* out = (float*)d_out;
  char* ws = (char*)d_ws;

  unsigned short* Yb  = (unsigned short*)ws;                       // 8192*144*2 = 2359296
  unsigned short* VbT = (unsigned short*)(ws + 2359296);           // 144*4096*2 = 1179648
  float* Q        = (float*)(ws + 2359296 + 1179648);              // QS*QS*4 = 82944
  float* colsum   = (float*)(ws + 2359296 + 1179648 + 82944);      // D*4
  float* colsumsq = colsum + D;                                    // D*4
  float* M        = colsumsq + D;                                  // KP*MS*4
  float* tvec     = M + KP * MS;
  float* mvec     = tvec + MS;
  float* scalars  = mvec + MS;                                     // 8 floats
  float* Gg       = scalars + 8;                                   // NP*NP = 17424

  // zero atomic accumulators: Q + colsum + colsumsq (contiguous)
  hipMemsetAsync(Q, 0, (size_t)(QS * QS + 2 * D) * sizeof(float), stream);

  k_prep   <<<dim3(NC), 256, 0, stream>>>(theta, VbT);
  k_M      <<<dim3(KP, KP), 256, 0, stream>>>(theta, VbT, M);
  k_par    <<<dim3(1 + GEMM_BLOCKS + CS_BLOCKS), 1024, 0, stream>>>(
               x, VbT, Yb, M, Gg, scalars, colsum, colsumsq);
  k_syrk   <<<dim3(QS / 16, QS / 16, SYRK_ZSPLIT), 256, 0, stream>>>(Yb, Q);
  k_small  <<<dim3(2 * KP + 1), 256, 0, stream>>>(theta, VbT, colsum, colsumsq,
                                                  tvec, mvec, scalars);
  k_trace  <<<dim3(9, 9), 256, 0, stream>>>(Gg, Q, tvec, mvec, scalars);
  k_combine<<<dim3(1), 64, 0, stream>>>(scalars, fds, out);
}

// Round 11
// 197.047 us; speedup vs baseline: 1.1162x; 1.1162x over previous
//
#include <hip/hip_runtime.h>
#include <math.h>

#define D 4096
#define K 128
#define KP 129          // K+1 (augmented sqrt(EPS)*ones column)
#define NC 144          // padded col count for VbT / Yb (9 tiles of 16; cols >= 129 zero)
#define NROWS 8192
#define QS 144          // Q row stride
#define MS 132          // M row stride
#define NP 132          // padded order for chol
#define NPS 136         // LDS row stride (float4-aligned)
#define NB 12           // panel width (11 panels)
#define NPAN (NP / NB)
#define LOG2PI 1.8378770664093453

typedef __attribute__((ext_vector_type(8))) short bh8;     // 8 bf16 (4 VGPRs)
typedef __attribute__((ext_vector_type(4))) float f32x4;   // MFMA acc

// ---------------- helpers ----------------
__device__ __forceinline__ unsigned short f2bf(float f) {  // RNE
  unsigned int u = __float_as_uint(f);
  unsigned int r = u + 0x7FFFu + ((u >> 16) & 1u);
  return (unsigned short)(r >> 16);
}
__device__ __forceinline__ float bf2f(unsigned short u) {
  return __uint_as_float(((unsigned int)u) << 16);
}
__device__ __forceinline__ float blo(unsigned int v) { return __uint_as_float(v << 16); }
__device__ __forceinline__ float bhi(unsigned int v) { return __uint_as_float(v & 0xFFFF0000u); }

__device__ __forceinline__ float blockReduceSum256(float v) {
  #pragma unroll
  for (int off = 32; off > 0; off >>= 1) v += __shfl_down(v, off, 64);
  __shared__ float tmp[4];
  __syncthreads();
  if ((threadIdx.x & 63) == 0) tmp[threadIdx.x >> 6] = v;
  __syncthreads();
  float r = 0.0f;
  if (threadIdx.x == 0) r = tmp[0] + tmp[1] + tmp[2] + tmp[3];
  return r;                              // valid on tid 0 only
}

// ---------------- VbT[c][d] = bf16( U[d][c] / sigma[d] ), rows c>=129 zero ----------------
__global__ __launch_bounds__(256) void k_prep(const float* __restrict__ theta,
                                              unsigned short* __restrict__ VbT) {
  int c = blockIdx.x;                    // 0..143
  const float* sg = theta + (size_t)D * K + D;
  float al = (c < K) ? theta[(size_t)D * K + 2 * D + c] : 0.0f;
  for (int d = threadIdx.x; d < D; d += 256) {
    float v;
    if (c < K)       v = theta[(size_t)d * K + c] * al / sg[d];
    else if (c == K) v = 1.0e-3f / sg[d];
    else             v = 0.0f;
    VbT[(size_t)c * D + d] = f2bf(v);
  }
}

// ---------------- M = I + sum_d sigma_d VbT[j][d] VbT[k][d] ----------------
__global__ __launch_bounds__(256) void k_M(const float* __restrict__ theta,
                                           const unsigned short* __restrict__ VbT,
                                           float* __restrict__ M) {
  int j = blockIdx.x, kk2 = blockIdx.y;
  if (kk2 < j) return;                   // symmetry
  const float* sg = theta + (size_t)D * K + D;
  float acc = 0.0f;
  for (int d0 = threadIdx.x * 8; d0 < D; d0 += 2048) {
    uint4 ua = *reinterpret_cast<const uint4*>(&VbT[(size_t)j * D + d0]);
    uint4 ub = *reinterpret_cast<const uint4*>(&VbT[(size_t)kk2 * D + d0]);
    float4 s0 = *reinterpret_cast<const float4*>(&sg[d0]);
    float4 s1 = *reinterpret_cast<const float4*>(&sg[d0 + 4]);
    acc += s0.x * blo(ua.x) * blo(ub.x) + s0.y * bhi(ua.x) * bhi(ub.x)
         + s0.z * blo(ua.y) * blo(ub.y) + s0.w * bhi(ua.y) * bhi(ub.y)
         + s1.x * blo(ua.z) * blo(ub.z) + s1.y * bhi(ua.z) * bhi(ub.z)
         + s1.z * blo(ua.w) * blo(ub.w) + s1.w * bhi(ua.w) * bhi(ub.w);
  }
  float r = blockReduceSum256(acc);
  if (threadIdx.x == 0) {
    float m = r + (j == kk2 ? 1.0f : 0.0f);
    M[j * MS + kk2] = m;
    M[kk2 * MS + j] = m;
  }
}

// ---------------- fused: tvec (b<KP), mvec (KP<=b<2KP), scalars (b==2KP) ----------------
__global__ __launch_bounds__(256) void k_small(const float* __restrict__ theta,
                                               const unsigned short* __restrict__ VbT,
                                               const float* __restrict__ colsum,
                                               const float* __restrict__ colsumsq,
                                               float* __restrict__ tvec,
                                               float* __restrict__ mvec,
                                               float* __restrict__ scalars) {
  int b = blockIdx.x;
  if (b < 2 * KP) {
    int c = (b >= KP) ? b - KP : b;
    const float* src = (b >= KP) ? (theta + (size_t)D * K) : colsum;
    float a = 0.0f;
    for (int d = threadIdx.x; d < D; d += 256) a += bf2f(VbT[(size_t)c * D + d]) * src[d];
    float r = blockReduceSum256(a);
    if (threadIdx.x == 0) { if (b < KP) tvec[c] = r; else mvec[c] = r; }
  } else {
    const float* mu = theta + (size_t)D * K;
    const float* sg = theta + (size_t)D * K + D;
    float a = 0.0f, bb = 0.0f;
    for (int d = threadIdx.x; d < D; d += 256) {
      float s = sg[d];
      float m = mu[d];
      a += logf(s);
      bb += (colsumsq[d] - 2.0f * m * colsum[d] + (float)NROWS * m * m) / s;
    }
    float ra = blockReduceSum256(a);
    float rb = blockReduceSum256(bb);
    if (threadIdx.x == 0) { scalars[0] = ra; scalars[1] = rb; }
  }
}

// ================= fused parallel kernel: chol (block 0) | gemm (1..256) | colstats =================
#define GBM 32
#define GBK 128
#define NSTEP (D / GBK)     // 32
#define XSS 136             // LDS row stride in shorts
#define GEMM_BLOCKS (NROWS / GBM)   // 256
#define CS_BLOCKS 32
#define CS_ROWS (NROWS / CS_BLOCKS) // 256

struct CholSh {
  float A[NP][NPS];
  float G[NP][NPS];
  float Tst[NPAN][NB][NB + 1];
};
struct GemmSh {
  unsigned short Xs[GBM][XSS];
  unsigned short Vs[NC][XSS];
};
union ParSh {
  CholSh c;
  GemmSh g;
};

__device__ void chol_body(CholSh& sh, const float* __restrict__ Mg,
                          float* __restrict__ Gg, float* __restrict__ scalars) {
  auto& A = sh.A;
  auto& G = sh.G;
  auto& Tst = sh.Tst;
  __shared__ float redB[16];
  int tid = threadIdx.x;

  if (tid == 0) scalars[3] = 0.0f;       // trace accumulator for k_trace
  for (int idx = tid; idx < NP * NP; idx += 1024) {
    int r = idx / NP, c = idx - r * NP;
    A[r][c] = (r < KP && c < KP) ? Mg[r * MS + c] : (r == c ? 1.0f : 0.0f);
  }
  __syncthreads();

  // ---- blocked Cholesky with fused triangular inverse (disjoint-thread overlap) ----
  for (int p = 0; p < NPAN; ++p) {
    int j0 = p * NB, j1 = j0 + NB;
    int nbrows = NP - j1;
    int nG = p * NB;                     // threads doing G-apply in phase 2
    // ---- phase 1: {diag chol+inv + panel solve} on 0..127  ||  T2 accum on 128..128+nG ----
    if (tid < 128) {
      float T[NB][NB];
      #pragma unroll
      for (int r = 0; r < NB; ++r)
        #pragma unroll
        for (int c = 0; c <= r; ++c)
          T[r][c] = A[j0 + r][j0 + c];
      float dinv[NB];
      #pragma unroll
      for (int jj = 0; jj < NB; ++jj) {
        float dv = sqrtf(T[jj][jj]);
        float iv = 1.0f / dv;
        dinv[jj] = iv;
        #pragma unroll
        for (int r = jj + 1; r < NB; ++r) T[r][jj] *= iv;
        #pragma unroll
        for (int cc = jj + 1; cc < NB; ++cc)
          #pragma unroll
          for (int r = cc; r < NB; ++r)
            T[r][cc] -= T[r][jj] * T[cc][jj];
      }
      #pragma unroll
      for (int r = 0; r < NB; ++r) {     // in-place row-wise inverse -> G_pp
        float tmp[NB];
        #pragma unroll
        for (int c = 0; c < r; ++c) {
          float s = 0.0f;
          #pragma unroll
          for (int k = c; k < r; ++k) s += T[r][k] * T[k][c];
          tmp[c] = -s * dinv[r];
        }
        #pragma unroll
        for (int c = 0; c < r; ++c) T[r][c] = tmp[c];
        T[r][r] = dinv[r];
      }
      if (tid == 0) {                    // stash G_pp (upper zeros)
        #pragma unroll
        for (int r = 0; r < NB; ++r) {
          float g[NB];
          #pragma unroll
          for (int c = 0; c < NB; ++c) g[c] = (c <= r) ? T[r][c] : 0.0f;
          float4* dst = reinterpret_cast<float4*>(&G[j0 + r][j0]);
          float4 g0 = {g[0], g[1], g[2], g[3]};
          float4 g1 = {g[4], g[5], g[6], g[7]};
          float4 g2 = {g[8], g[9], g[10], g[11]};
          dst[0] = g0; dst[1] = g1; dst[2] = g2;
        }
      }
      if (tid < nbrows) {                // fused panel solve, G_pp from registers
        int r = j1 + tid;
        float* arow = &A[r][j0];
        float4 q0 = *reinterpret_cast<const float4*>(arow);
        float4 q1 = *reinterpret_cast<const float4*>(arow + 4);
        float4 q2 = *reinterpret_cast<const float4*>(arow + 8);
        float ro[NB] = {q0.x, q0.y, q0.z, q0.w, q1.x, q1.y, q1.z, q1.w,
                        q2.x, q2.y, q2.z, q2.w};
        float rn[NB];
        #pragma unroll
        for (int cc = 0; cc < NB; ++cc) {
          float s = 0.0f;
          #pragma unroll
          for (int k = 0; k <= cc; ++k) s += ro[k] * T[cc][k];
          rn[cc] = s;
        }
        float4 w0 = {rn[0], rn[1], rn[2], rn[3]};
        float4 w1 = {rn[4], rn[5], rn[6], rn[7]};
        float4 w2 = {rn[8], rn[9], rn[10], rn[11]};
        *reinterpret_cast<float4*>(arow) = w0;
        *reinterpret_cast<float4*>(arow + 4) = w1;
        *reinterpret_cast<float4*>(arow + 8) = w2;
      }
    } else if (tid < 128 + nG) {
      // T2[q][m][j] = sum_{k=q..p-1} sum_n L[j0+m][kI+n] * G[kI+n][qI+j]
      // inputs final: L cols < j0 (panels < p), G row-blocks < p
      int t2 = tid - 128;
      int q = t2 / NB, j = t2 - q * NB;
      int qI = q * NB;
      float T2[NB] = {0, 0, 0, 0, 0, 0, 0, 0, 0, 0, 0, 0};
      for (int k = q; k < p; ++k) {
        int kI = k * NB;
        #pragma unroll
        for (int n = 0; n < NB; ++n) {
          float g = G[kI + n][qI + j];
          #pragma unroll
          for (int m = 0; m < NB; ++m) T2[m] += A[j0 + m][kI + n] * g;
        }
      }
      #pragma unroll
      for (int m = 0; m < NB; ++m) Tst[q][m][j] = T2[m];
    }
    __syncthreads();
    // ---- phase 2: G-apply on 0..nG-1  ||  trailing update on nG..1023 (disjoint) ----
    if (tid < nG) {
      int q = tid / NB, j = tid - (tid / NB) * NB;
      int qI = q * NB;
      float w[NB];
      #pragma unroll
      for (int m = 0; m < NB; ++m) w[m] = Tst[q][m][j];
      #pragma unroll
      for (int i = 0; i < NB; ++i) {
        float s = 0.0f;
        #pragma unroll
        for (int m = 0; m <= i; ++m) s += G[j0 + i][j0 + m] * w[m];
        G[j0 + i][qI + j] = -s;
      }
    } else {
      int nt = nbrows / 4;
      int ntasks = nt * (nt + 1) / 2;
      int nthr = 1024 - nG;
      for (int t = tid - nG; t < ntasks; t += nthr) {
        int r4 = (int)((sqrtf(8.0f * (float)t + 1.0f) - 1.0f) * 0.5f);
        while ((r4 + 1) * (r4 + 2) / 2 <= t) ++r4;
        while (r4 * (r4 + 1) / 2 > t) --r4;
        int c4 = t - r4 * (r4 + 1) / 2;
        int r = j1 + r4 * 4, c = j1 + c4 * 4;
        float pr[4][NB], pc[4][NB];
        #pragma unroll
        for (int i = 0; i < 4; ++i) {
          float4 a0 = *reinterpret_cast<const float4*>(&A[r + i][j0]);
          float4 a1 = *reinterpret_cast<const float4*>(&A[r + i][j0 + 4]);
          float4 a2 = *reinterpret_cast<const float4*>(&A[r + i][j0 + 8]);
          pr[i][0] = a0.x; pr[i][1] = a0.y; pr[i][2] = a0.z; pr[i][3] = a0.w;
          pr[i][4] = a1.x; pr[i][5] = a1.y; pr[i][6] = a1.z; pr[i][7] = a1.w;
          pr[i][8] = a2.x; pr[i][9] = a2.y; pr[i][10] = a2.z; pr[i][11] = a2.w;
          float4 b0 = *reinterpret_cast<const float4*>(&A[c + i][j0]);
          float4 b1 = *reinterpret_cast<const float4*>(&A[c + i][j0 + 4]);
          float4 b2 = *reinterpret_cast<const float4*>(&A[c + i][j0 + 8]);
          pc[i][0] = b0.x; pc[i][1] = b0.y; pc[i][2] = b0.z; pc[i][3] = b0.w;
          pc[i][4] = b1.x; pc[i][5] = b1.y; pc[i][6] = b1.z; pc[i][7] = b1.w;
          pc[i][8] = b2.x; pc[i][9] = b2.y; pc[i][10] = b2.z; pc[i][11] = b2.w;
        }
        float4 av[4];
        #pragma unroll
        for (int i = 0; i < 4; ++i)
          av[i] = *reinterpret_cast<const float4*>(&A[r + i][c]);
        #pragma unroll
        for (int k = 0; k < NB; ++k) {
          #pragma unroll
          for (int i = 0; i < 4; ++i) {
            av[i].x -= pr[i][k] * pc[0][k];
            av[i].y -= pr[i][k] * pc[1][k];
            av[i].z -= pr[i][k] * pc[2][k];
            av[i].w -= pr[i][k] * pc[3][k];
          }
        }
        #pragma unroll
        for (int i = 0; i < 4; ++i)
          *reinterpret_cast<float4*>(&A[r + i][c]) = av[i];
      }
    }
    __syncthreads();
  }

  // ---- write G to global ----
  for (int idx = tid; idx < NP * NP; idx += 1024) {
    int r = idx / NP, c = idx - r * NP;
    Gg[idx] = G[r][c];
  }

  // ---- logdet from diag(G) = 1/diag(L) ----
  float lg = (tid < NP) ? logf(G[tid][tid]) : 0.0f;
  #pragma unroll
  for (int off = 32; off > 0; off >>= 1) lg += __shfl_down(lg, off, 64);
  __syncthreads();
  if ((tid & 63) == 0) redB[tid >> 6] = lg;
  __syncthreads();
  if (tid == 0) {
    float sgl = 0.0f;
    #pragma unroll
    for (int i = 0; i < 16; ++i) sgl += redB[i];
    scalars[2] = -2.0f * sgl;            // logdet(M)
  }
}

__device__ void gemm_body(GemmSh& sh, const float* __restrict__ x,
                          const unsigned short* __restrict__ VbT,
                          unsigned short* __restrict__ Yb, int blk) {
  auto& Xs = sh.Xs;
  auto& Vs = sh.Vs;
  int tid = threadIdx.x;                 // < 512
  int row0 = blk * GBM;
  int wid = tid >> 6, lane = tid & 63;
  int lr = lane & 15, lk = (lane >> 4) * 8;
  int rt = wid & 1;
  int cg = wid >> 1;
  int ct0 = (cg == 0) ? 0 : (cg * 2 + 1);
  int nct = (cg == 0) ? 3 : 2;

  int sxr = tid >> 4;
  int sxk = (tid & 15) * 8;
  int vrb = tid >> 4;
  int vk  = (tid & 15) * 8;

  float4 xr0, xr1;
  uint4 vr0, vr1, vr2, vr3, vr4;
  {
    const float* xb = &x[(size_t)(row0 + sxr) * D + sxk];
    xr0 = *reinterpret_cast<const float4*>(xb);
    xr1 = *reinterpret_cast<const float4*>(xb + 4);
    const unsigned short* vb = &VbT[(size_t)vrb * D + vk];
    vr0 = *reinterpret_cast<const uint4*>(vb);
    vr1 = *reinterpret_cast<const uint4*>(vb + (size_t)32 * D);
    vr2 = *reinterpret_cast<const uint4*>(vb + (size_t)64 * D);
    vr3 = *reinterpret_cast<const uint4*>(vb + (size_t)96 * D);
    if (tid < 256) vr4 = *reinterpret_cast<const uint4*>(vb + (size_t)128 * D);
  }

  f32x4 acc0 = {0, 0, 0, 0}, acc1 = {0, 0, 0, 0}, acc2 = {0, 0, 0, 0};

  for (int s = 0; s < NSTEP; ++s) {
    {
      uint4 w;
      w.x = (unsigned)f2bf(xr0.x) | ((unsigned)f2bf(xr0.y) << 16);
      w.y = (unsigned)f2bf(xr0.z) | ((unsigned)f2bf(xr0.w) << 16);
      w.z = (unsigned)f2bf(xr1.x) | ((unsigned)f2bf(xr1.y) << 16);
      w.w = (unsigned)f2bf(xr1.z) | ((unsigned)f2bf(xr1.w) << 16);
      *reinterpret_cast<uint4*>(&Xs[sxr][sxk]) = w;
      unsigned short* vd = &Vs[vrb][vk];
      *reinterpret_cast<uint4*>(vd) = vr0;
      *reinterpret_cast<uint4*>(vd + 32 * XSS) = vr1;
      *reinterpret_cast<uint4*>(vd + 64 * XSS) = vr2;
      *reinterpret_cast<uint4*>(vd + 96 * XSS) = vr3;
      if (tid < 256) *reinterpret_cast<uint4*>(vd + 128 * XSS) = vr4;
    }
    __syncthreads();
    if (s + 1 < NSTEP) {
      const float* xb = &x[(size_t)(row0 + sxr) * D + (s + 1) * GBK + sxk];
      xr0 = *reinterpret_cast<const float4*>(xb);
      xr1 = *reinterpret_cast<const float4*>(xb + 4);
      const unsigned short* vb = &VbT[(size_t)vrb * D + (s + 1) * GBK + vk];
      vr0 = *reinterpret_cast<const uint4*>(vb);
      vr1 = *reinterpret_cast<const uint4*>(vb + (size_t)32 * D);
      vr2 = *reinterpret_cast<const uint4*>(vb + (size_t)64 * D);
      vr3 = *reinterpret_cast<const uint4*>(vb + (size_t)96 * D);
      if (tid < 256) vr4 = *reinterpret_cast<const uint4*>(vb + (size_t)128 * D);
    }
    #pragma unroll
    for (int ks = 0; ks < 4; ++ks) {
      bh8 a = *reinterpret_cast<const bh8*>(&Xs[rt * 16 + lr][ks * 32 + lk]);
      bh8 b0 = *reinterpret_cast<const bh8*>(&Vs[ct0 * 16 + lr][ks * 32 + lk]);
      acc0 = __builtin_amdgcn_mfma_f32_16x16x32_bf16(a, b0, acc0, 0, 0, 0);
      bh8 b1 = *reinterpret_cast<const bh8*>(&Vs[(ct0 + 1) * 16 + lr][ks * 32 + lk]);
      acc1 = __builtin_amdgcn_mfma_f32_16x16x32_bf16(a, b1, acc1, 0, 0, 0);
      if (nct == 3) {
        bh8 b2 = *reinterpret_cast<const bh8*>(&Vs[(ct0 + 2) * 16 + lr][ks * 32 + lk]);
        acc2 = __builtin_amdgcn_mfma_f32_16x16x32_bf16(a, b2, acc2, 0, 0, 0);
      }
    }
    __syncthreads();
  }

  int rw = row0 + rt * 16 + ((lane >> 4) << 2);
  #pragma unroll
  for (int g = 0; g < 4; ++g)
    Yb[(size_t)(rw + g) * NC + ct0 * 16 + lr] = f2bf(acc0[g]);
  #pragma unroll
  for (int g = 0; g < 4; ++g)
    Yb[(size_t)(rw + g) * NC + (ct0 + 1) * 16 + lr] = f2bf(acc1[g]);
  if (nct == 3) {
    #pragma unroll
    for (int g = 0; g < 4; ++g)
      Yb[(size_t)(rw + g) * NC + (ct0 + 2) * 16 + lr] = f2bf(acc2[g]);
  }
}

__device__ void colstats_body(const float* __restrict__ x,
                              float* __restrict__ colsum,
                              float* __restrict__ colsumsq, int cb) {
  int d4 = threadIdx.x;                  // 0..1023 covers D/4
  int i0 = cb * CS_ROWS;
  float4 s1 = {0, 0, 0, 0}, s2 = {0, 0, 0, 0};
  for (int i = i0; i < i0 + CS_ROWS; ++i) {
    float4 v = *reinterpret_cast<const float4*>(&x[(size_t)i * D + d4 * 4]);
    s1.x += v.x; s1.y += v.y; s1.z += v.z; s1.w += v.w;
    s2.x += v.x * v.x; s2.y += v.y * v.y; s2.z += v.z * v.z; s2.w += v.w * v.w;
  }
  atomicAdd(&colsum[d4 * 4 + 0], s1.x); atomicAdd(&colsum[d4 * 4 + 1], s1.y);
  atomicAdd(&colsum[d4 * 4 + 2], s1.z); atomicAdd(&colsum[d4 * 4 + 3], s1.w);
  atomicAdd(&colsumsq[d4 * 4 + 0], s2.x); atomicAdd(&colsumsq[d4 * 4 + 1], s2.y);
  atomicAdd(&colsumsq[d4 * 4 + 2], s2.z); atomicAdd(&colsumsq[d4 * 4 + 3], s2.w);
}

__global__ __launch_bounds__(1024, 1) void k_par(const float* __restrict__ x,
                                                 const unsigned short* __restrict__ VbT,
                                                 unsigned short* __restrict__ Yb,
                                                 const float* __restrict__ Mg,
                                                 float* __restrict__ Gg,
                                                 float* __restrict__ scalars,
                                                 float* __restrict__ colsum,
                                                 float* __restrict__ colsumsq) {
  __shared__ ParSh sh;
  int b = blockIdx.x;
  if (b == 0) {
    chol_body(sh.c, Mg, Gg, scalars);
  } else if (b <= GEMM_BLOCKS) {
    if (threadIdx.x >= 512) return;      // exit before any barrier
    gemm_body(sh.g, x, VbT, Yb, b - 1);
  } else {
    colstats_body(x, colsum, colsumsq, b - 1 - GEMM_BLOCKS);
  }
}

// ---------------- Q += Yb^T Yb  (bf16 in, symmetry, row-split atomics) ----------------
#define SYRK_ZSPLIT 16
__global__ __launch_bounds__(256) void k_syrk(const unsigned short* __restrict__ Yb,
                                              float* __restrict__ Q) {
  int bj = blockIdx.x * 16, bk = blockIdx.y * 16;
  if (bk < bj) return;                   // symmetry
  __shared__ float Ya[64][17];
  __shared__ float Yc[64][17];
  int i0base = blockIdx.z * (NROWS / SYRK_ZSPLIT);
  int tid = threadIdx.x;
  int tj = tid & 15, tk = tid >> 4;
  int lr = tid >> 2, lc = (tid & 3) * 4;
  float acc = 0.0f;
  for (int i0 = i0base; i0 < i0base + NROWS / SYRK_ZSPLIT; i0 += 64) {
    ushort4 va = *reinterpret_cast<const ushort4*>(&Yb[(size_t)(i0 + lr) * NC + bj + lc]);
    ushort4 vc = *reinterpret_cast<const ushort4*>(&Yb[(size_t)(i0 + lr) * NC + bk + lc]);
    Ya[lr][lc + 0] = bf2f(va.x); Ya[lr][lc + 1] = bf2f(va.y);
    Ya[lr][lc + 2] = bf2f(va.z); Ya[lr][lc + 3] = bf2f(va.w);
    Yc[lr][lc + 0] = bf2f(vc.x); Yc[lr][lc + 1] = bf2f(vc.y);
    Yc[lr][lc + 2] = bf2f(vc.z); Yc[lr][lc + 3] = bf2f(vc.w);
    __syncthreads();
    #pragma unroll
    for (int ii = 0; ii < 64; ++ii) acc += Ya[ii][tj] * Yc[ii][tk];
    __syncthreads();
  }
  atomicAdd(&Q[(bj + tj) * QS + bk + tk], acc);
  if (bj != bk) atomicAdd(&Q[(bk + tk) * QS + bj + tj], acc);
}

// ---------------- k_trace: tr(M^-1 S) = sum_{j<=k} (2-d) H_jk S_jk, H = G^T G ----------------
__global__ __launch_bounds__(256) void k_trace(const float* __restrict__ Gg,
                                               const float* __restrict__ Qg,
                                               const float* __restrict__ tvec,
                                               const float* __restrict__ mvec,
                                               float* __restrict__ scalars) {
  int bj = blockIdx.x * 16, bk = blockIdx.y * 16;
  if (bk < bj) return;                   // upper tiles only
  int tj = threadIdx.x & 15, tk = threadIdx.x >> 4;
  int j = bj + tj, k = bk + tk;
  float acc = 0.0f;
  if (j <= k && k < NP) {
    float h0 = 0.f, h1 = 0.f;
    int i = k;
    for (; i + 1 < NP; i += 2) {
      h0 += Gg[(size_t)i * NP + j] * Gg[(size_t)i * NP + k];
      h1 += Gg[(size_t)(i + 1) * NP + j] * Gg[(size_t)(i + 1) * NP + k];
    }
    for (; i < NP; ++i) h0 += Gg[(size_t)i * NP + j] * Gg[(size_t)i * NP + k];
    float h = h0 + h1;
    float S = 0.0f;
    if (j < KP && k < KP) {
      float tlj = tvec[j], mlj = mvec[j], tlk = tvec[k], mlk = mvec[k];
      S = Qg[j * QS + k] - tlj * mlk - mlj * tlk + (float)NROWS * mlj * mlk;
    }
    acc = ((j == k) ? 1.0f : 2.0f) * h * S;
  }
  float r = blockReduceSum256(acc);
  if (threadIdx.x == 0) atomicAdd(&scalars[3], r);
}

// ---------------- k_combine ----------------
__global__ void k_combine(const float* __restrict__ scalars,
                          const int* __restrict__ fds,
                          float* __restrict__ out) {
  if (threadIdx.x == 0) {
    double sumlog  = (double)scalars[0];
    double term1   = (double)scalars[1];
    double logdetM = (double)scalars[2];
    double tr      = (double)scalars[3];
    double total = (double)NROWS * (double)D * LOG2PI
                 + (double)NROWS * (sumlog + logdetM)
                 + term1 - tr;
    double scale = (double)fds[0] / (double)NROWS;
    out[0] = (float)(scale * (-0.5) * total);
  }
}

// ---------------- launch ----------------
extern "C" void kernel_launch(void* const* d_in, const int* in_sizes, int n_in,
                              void* d_out, int out_size, void* d_ws, size_t ws_size,
                              hipStream_t stream) {
  const float* x     = (const float*)d_in[0];
  const float* theta = (const float*)d_in[1];
  const int*   fds   = (const int*)d_in[2];
  float* out = (float*)d_out;
  char* ws = (char*)d_ws;

  unsigned short* Yb  = (unsigned short*)ws;                       // 8192*144*2 = 2359296
  unsigned short* VbT = (unsigned short*)(ws + 2359296);           // 144*4096*2 = 1179648
  float* Q        = (float*)(ws + 2359296 + 1179648);              // QS*QS*4 = 82944
  float* colsum   = (float*)(ws + 2359296 + 1179648 + 82944);      // D*4
  float* colsumsq = colsum + D;                                    // D*4
  float* M        = colsumsq + D;                                  // KP*MS*4
  float* tvec     = M + KP * MS;
  float* mvec     = tvec + MS;
  float* scalars  = mvec + MS;                                     // 8 floats
  float* Gg       = scalars + 8;                                   // NP*NP = 17424

  // zero atomic accumulators: Q + colsum + colsumsq (contiguous)
  hipMemsetAsync(Q, 0, (size_t)(QS * QS + 2 * D) * sizeof(float), stream);

  k_prep   <<<dim3(NC), 256, 0, stream>>>(theta, VbT);
  k_M      <<<dim3(KP, KP), 256, 0, stream>>>(theta, VbT, M);
  k_par    <<<dim3(1 + GEMM_BLOCKS + CS_BLOCKS), 1024, 0, stream>>>(
               x, VbT, Yb, M, Gg, scalars, colsum, colsumsq);
  k_syrk   <<<dim3(QS / 16, QS / 16, SYRK_ZSPLIT), 256, 0, stream>>>(Yb, Q);
  k_small  <<<dim3(2 * KP + 1), 256, 0, stream>>>(theta, VbT, colsum, colsumsq,
                                                  tvec, mvec, scalars);
  k_trace  <<<dim3(9, 9), 256, 0, stream>>>(Gg, Q, tvec, mvec, scalars);
  k_combine<<<dim3(1), 64, 0, stream>>>(scalars, fds, out);
}

// Round 12
// 163.712 us; speedup vs baseline: 1.3434x; 1.2036x over previous
//
#include <hip/hip_runtime.h>
#include <math.h>

#define D 4096
#define K 128
#define KP 129          // K+1 (augmented sqrt(EPS)*ones column)
#define NC 144          // padded col count for VbT / Yb (9 tiles of 16; cols >= 129 zero)
#define NROWS 8192
#define QS 144          // Q row stride
#define MS 132          // M row stride
#define NP 132          // padded order for chol
#define NPS 136         // LDS row stride (float4-aligned)
#define NB 12           // panel width (11 panels)
#define NPAN (NP / NB)
#define MSPLIT 6        // T2 accumulation row-split (2 rows/thread)
#define LOG2PI 1.8378770664093453

typedef __attribute__((ext_vector_type(8))) short bh8;     // 8 bf16 (4 VGPRs)
typedef __attribute__((ext_vector_type(4))) float f32x4;   // MFMA acc

// ---------------- helpers ----------------
__device__ __forceinline__ unsigned short f2bf(float f) {  // RNE
  unsigned int u = __float_as_uint(f);
  unsigned int r = u + 0x7FFFu + ((u >> 16) & 1u);
  return (unsigned short)(r >> 16);
}
__device__ __forceinline__ float bf2f(unsigned short u) {
  return __uint_as_float(((unsigned int)u) << 16);
}
__device__ __forceinline__ float blo(unsigned int v) { return __uint_as_float(v << 16); }
__device__ __forceinline__ float bhi(unsigned int v) { return __uint_as_float(v & 0xFFFF0000u); }

__device__ __forceinline__ float blockReduceSum256(float v) {
  #pragma unroll
  for (int off = 32; off > 0; off >>= 1) v += __shfl_down(v, off, 64);
  __shared__ float tmp[4];
  __syncthreads();
  if ((threadIdx.x & 63) == 0) tmp[threadIdx.x >> 6] = v;
  __syncthreads();
  float r = 0.0f;
  if (threadIdx.x == 0) r = tmp[0] + tmp[1] + tmp[2] + tmp[3];
  return r;                              // valid on tid 0 only
}

// ---------------- VbT[c][d] = bf16( U[d][c] / sigma[d] ), rows c>=129 zero ----------------
__global__ __launch_bounds__(256) void k_prep(const float* __restrict__ theta,
                                              unsigned short* __restrict__ VbT) {
  int c = blockIdx.x;                    // 0..143
  const float* sg = theta + (size_t)D * K + D;
  float al = (c < K) ? theta[(size_t)D * K + 2 * D + c] : 0.0f;
  for (int d = threadIdx.x; d < D; d += 256) {
    float v;
    if (c < K)       v = theta[(size_t)d * K + c] * al / sg[d];
    else if (c == K) v = 1.0e-3f / sg[d];
    else             v = 0.0f;
    VbT[(size_t)c * D + d] = f2bf(v);
  }
}

// ---------------- M = I + sum_d sigma_d VbT[j][d] VbT[k][d] ----------------
__global__ __launch_bounds__(256) void k_M(const float* __restrict__ theta,
                                           const unsigned short* __restrict__ VbT,
                                           float* __restrict__ M) {
  int j = blockIdx.x, kk2 = blockIdx.y;
  if (kk2 < j) return;                   // symmetry
  const float* sg = theta + (size_t)D * K + D;
  float acc = 0.0f;
  for (int d0 = threadIdx.x * 8; d0 < D; d0 += 2048) {
    uint4 ua = *reinterpret_cast<const uint4*>(&VbT[(size_t)j * D + d0]);
    uint4 ub = *reinterpret_cast<const uint4*>(&VbT[(size_t)kk2 * D + d0]);
    float4 s0 = *reinterpret_cast<const float4*>(&sg[d0]);
    float4 s1 = *reinterpret_cast<const float4*>(&sg[d0 + 4]);
    acc += s0.x * blo(ua.x) * blo(ub.x) + s0.y * bhi(ua.x) * bhi(ub.x)
         + s0.z * blo(ua.y) * blo(ub.y) + s0.w * bhi(ua.y) * bhi(ub.y)
         + s1.x * blo(ua.z) * blo(ub.z) + s1.y * bhi(ua.z) * bhi(ub.z)
         + s1.z * blo(ua.w) * blo(ub.w) + s1.w * bhi(ua.w) * bhi(ub.w);
  }
  float r = blockReduceSum256(acc);
  if (threadIdx.x == 0) {
    float m = r + (j == kk2 ? 1.0f : 0.0f);
    M[j * MS + kk2] = m;
    M[kk2 * MS + j] = m;
  }
}

// ---------------- fused: tvec (b<KP), mvec (KP<=b<2KP), scalars (b==2KP) ----------------
__global__ __launch_bounds__(256) void k_small(const float* __restrict__ theta,
                                               const unsigned short* __restrict__ VbT,
                                               const float* __restrict__ colsum,
                                               const float* __restrict__ colsumsq,
                                               float* __restrict__ tvec,
                                               float* __restrict__ mvec,
                                               float* __restrict__ scalars) {
  int b = blockIdx.x;
  if (b < 2 * KP) {
    int c = (b >= KP) ? b - KP : b;
    const float* src = (b >= KP) ? (theta + (size_t)D * K) : colsum;
    float a = 0.0f;
    for (int d = threadIdx.x; d < D; d += 256) a += bf2f(VbT[(size_t)c * D + d]) * src[d];
    float r = blockReduceSum256(a);
    if (threadIdx.x == 0) { if (b < KP) tvec[c] = r; else mvec[c] = r; }
  } else {
    const float* mu = theta + (size_t)D * K;
    const float* sg = theta + (size_t)D * K + D;
    float a = 0.0f, bb = 0.0f;
    for (int d = threadIdx.x; d < D; d += 256) {
      float s = sg[d];
      float m = mu[d];
      a += logf(s);
      bb += (colsumsq[d] - 2.0f * m * colsum[d] + (float)NROWS * m * m) / s;
    }
    float ra = blockReduceSum256(a);
    float rb = blockReduceSum256(bb);
    if (threadIdx.x == 0) { scalars[0] = ra; scalars[1] = rb; }
  }
}

// ================= fused parallel kernel: chol (block 0) | gemm (1..256) | colstats =================
#define GBM 32
#define GBK 128
#define NSTEP (D / GBK)     // 32
#define XSS 136             // LDS row stride in shorts
#define GEMM_BLOCKS (NROWS / GBM)   // 256
#define CS_BLOCKS 32
#define CS_ROWS (NROWS / CS_BLOCKS) // 256

struct CholSh {
  float A[NP][NPS];
  float G[NP][NPS];
  float Tst[NPAN][NB][NB + 1];
};
struct GemmSh {
  unsigned short Xs[GBM][XSS];
  unsigned short Vs[NC][XSS];
};
union ParSh {
  CholSh c;
  GemmSh g;
};

__device__ void chol_body(CholSh& sh, const float* __restrict__ Mg,
                          float* __restrict__ Gg, float* __restrict__ scalars) {
  auto& A = sh.A;
  auto& G = sh.G;
  auto& Tst = sh.Tst;
  __shared__ float redB[16];
  int tid = threadIdx.x;

  if (tid == 0) scalars[3] = 0.0f;       // trace accumulator for k_trace
  for (int idx = tid; idx < NP * NP; idx += 1024) {
    int r = idx / NP, c = idx - r * NP;
    A[r][c] = (r < KP && c < KP) ? Mg[r * MS + c] : (r == c ? 1.0f : 0.0f);
  }
  __syncthreads();

  // ---- blocked Cholesky with fused triangular inverse (disjoint-thread overlap) ----
  for (int p = 0; p < NPAN; ++p) {
    int j0 = p * NB, j1 = j0 + NB;
    int nbrows = NP - j1;
    int nG = p * NB;                     // threads doing G-apply in phase 2
    // ---- phase 1: {diag chol+inv + panel solve} on 0..127
    //              || m-split T2 accum on 128..128+MSPLIT*nG ----
    if (tid < 128) {
      float T[NB][NB];
      #pragma unroll
      for (int r = 0; r < NB; ++r)
        #pragma unroll
        for (int c = 0; c <= r; ++c)
          T[r][c] = A[j0 + r][j0 + c];
      float dinv[NB];
      #pragma unroll
      for (int jj = 0; jj < NB; ++jj) {
        float dv = sqrtf(T[jj][jj]);
        float iv = 1.0f / dv;
        dinv[jj] = iv;
        #pragma unroll
        for (int r = jj + 1; r < NB; ++r) T[r][jj] *= iv;
        #pragma unroll
        for (int cc = jj + 1; cc < NB; ++cc)
          #pragma unroll
          for (int r = cc; r < NB; ++r)
            T[r][cc] -= T[r][jj] * T[cc][jj];
      }
      #pragma unroll
      for (int r = 0; r < NB; ++r) {     // in-place row-wise inverse -> G_pp
        float tmp[NB];
        #pragma unroll
        for (int c = 0; c < r; ++c) {
          float s = 0.0f;
          #pragma unroll
          for (int k = c; k < r; ++k) s += T[r][k] * T[k][c];
          tmp[c] = -s * dinv[r];
        }
        #pragma unroll
        for (int c = 0; c < r; ++c) T[r][c] = tmp[c];
        T[r][r] = dinv[r];
      }
      if (tid == 0) {                    // stash G_pp (upper zeros)
        #pragma unroll
        for (int r = 0; r < NB; ++r) {
          float g[NB];
          #pragma unroll
          for (int c = 0; c < NB; ++c) g[c] = (c <= r) ? T[r][c] : 0.0f;
          float4* dst = reinterpret_cast<float4*>(&G[j0 + r][j0]);
          float4 g0 = {g[0], g[1], g[2], g[3]};
          float4 g1 = {g[4], g[5], g[6], g[7]};
          float4 g2 = {g[8], g[9], g[10], g[11]};
          dst[0] = g0; dst[1] = g1; dst[2] = g2;
        }
      }
      if (tid < nbrows) {                // fused panel solve, G_pp from registers
        int r = j1 + tid;
        float* arow = &A[r][j0];
        float4 q0 = *reinterpret_cast<const float4*>(arow);
        float4 q1 = *reinterpret_cast<const float4*>(arow + 4);
        float4 q2 = *reinterpret_cast<const float4*>(arow + 8);
        float ro[NB] = {q0.x, q0.y, q0.z, q0.w, q1.x, q1.y, q1.z, q1.w,
                        q2.x, q2.y, q2.z, q2.w};
        float rn[NB];
        #pragma unroll
        for (int cc = 0; cc < NB; ++cc) {
          float s = 0.0f;
          #pragma unroll
          for (int k = 0; k <= cc; ++k) s += ro[k] * T[cc][k];
          rn[cc] = s;
        }
        float4 w0 = {rn[0], rn[1], rn[2], rn[3]};
        float4 w1 = {rn[4], rn[5], rn[6], rn[7]};
        float4 w2 = {rn[8], rn[9], rn[10], rn[11]};
        *reinterpret_cast<float4*>(arow) = w0;
        *reinterpret_cast<float4*>(arow + 4) = w1;
        *reinterpret_cast<float4*>(arow + 8) = w2;
      }
    } else if (tid < 128 + MSPLIT * nG) {
      // T2[q][m][j] = sum_{k=q..p-1} sum_n L[j0+m][kI+n] * G[kI+n][qI+j]
      // thread (q, j, mg) owns rows m0 = mg*2, m0+1   (MSPLIT=6)
      int t2 = tid - 128;
      int q = t2 / (NB * MSPLIT);
      int rem = t2 - q * (NB * MSPLIT);
      int j = rem % NB, mg = rem / NB;
      int qI = q * NB;
      int m0 = mg * 2;
      float t0 = 0.0f, t1 = 0.0f;
      for (int k = q; k < p; ++k) {
        int kI = k * NB;
        #pragma unroll
        for (int n = 0; n < NB; ++n) {
          float g = G[kI + n][qI + j];
          t0 += A[j0 + m0 + 0][kI + n] * g;
          t1 += A[j0 + m0 + 1][kI + n] * g;
        }
      }
      Tst[q][m0 + 0][j] = t0;
      Tst[q][m0 + 1][j] = t1;
    }
    __syncthreads();
    // ---- phase 2: G-apply on 0..nG-1  ||  trailing update on nG..1023 (disjoint) ----
    if (tid < nG) {
      int q = tid / NB, j = tid - (tid / NB) * NB;
      int qI = q * NB;
      float w[NB];
      #pragma unroll
      for (int m = 0; m < NB; ++m) w[m] = Tst[q][m][j];
      #pragma unroll
      for (int i = 0; i < NB; ++i) {
        float s = 0.0f;
        #pragma unroll
        for (int m = 0; m <= i; ++m) s += G[j0 + i][j0 + m] * w[m];
        G[j0 + i][qI + j] = -s;
      }
    } else {
      int nt = nbrows / 4;
      int ntasks = nt * (nt + 1) / 2;
      int nthr = 1024 - nG;
      for (int t = tid - nG; t < ntasks; t += nthr) {
        int r4 = (int)((sqrtf(8.0f * (float)t + 1.0f) - 1.0f) * 0.5f);
        while ((r4 + 1) * (r4 + 2) / 2 <= t) ++r4;
        while (r4 * (r4 + 1) / 2 > t) --r4;
        int c4 = t - r4 * (r4 + 1) / 2;
        int r = j1 + r4 * 4, c = j1 + c4 * 4;
        float pr[4][NB], pc[4][NB];
        #pragma unroll
        for (int i = 0; i < 4; ++i) {
          float4 a0 = *reinterpret_cast<const float4*>(&A[r + i][j0]);
          float4 a1 = *reinterpret_cast<const float4*>(&A[r + i][j0 + 4]);
          float4 a2 = *reinterpret_cast<const float4*>(&A[r + i][j0 + 8]);
          pr[i][0] = a0.x; pr[i][1] = a0.y; pr[i][2] = a0.z; pr[i][3] = a0.w;
          pr[i][4] = a1.x; pr[i][5] = a1.y; pr[i][6] = a1.z; pr[i][7] = a1.w;
          pr[i][8] = a2.x; pr[i][9] = a2.y; pr[i][10] = a2.z; pr[i][11] = a2.w;
          float4 b0 = *reinterpret_cast<const float4*>(&A[c + i][j0]);
          float4 b1 = *reinterpret_cast<const float4*>(&A[c + i][j0 + 4]);
          float4 b2 = *reinterpret_cast<const float4*>(&A[c + i][j0 + 8]);
          pc[i][0] = b0.x; pc[i][1] = b0.y; pc[i][2] = b0.z; pc[i][3] = b0.w;
          pc[i][4] = b1.x; pc[i][5] = b1.y; pc[i][6] = b1.z; pc[i][7] = b1.w;
          pc[i][8] = b2.x; pc[i][9] = b2.y; pc[i][10] = b2.z; pc[i][11] = b2.w;
        }
        float4 av[4];
        #pragma unroll
        for (int i = 0; i < 4; ++i)
          av[i] = *reinterpret_cast<const float4*>(&A[r + i][c]);
        #pragma unroll
        for (int k = 0; k < NB; ++k) {
          #pragma unroll
          for (int i = 0; i < 4; ++i) {
            av[i].x -= pr[i][k] * pc[0][k];
            av[i].y -= pr[i][k] * pc[1][k];
            av[i].z -= pr[i][k] * pc[2][k];
            av[i].w -= pr[i][k] * pc[3][k];
          }
        }
        #pragma unroll
        for (int i = 0; i < 4; ++i)
          *reinterpret_cast<float4*>(&A[r + i][c]) = av[i];
      }
    }
    __syncthreads();
  }

  // ---- write G to global ----
  for (int idx = tid; idx < NP * NP; idx += 1024) {
    int r = idx / NP, c = idx - r * NP;
    Gg[idx] = G[r][c];
  }

  // ---- logdet from diag(G) = 1/diag(L) ----
  float lg = (tid < NP) ? logf(G[tid][tid]) : 0.0f;
  #pragma unroll
  for (int off = 32; off > 0; off >>= 1) lg += __shfl_down(lg, off, 64);
  __syncthreads();
  if ((tid & 63) == 0) redB[tid >> 6] = lg;
  __syncthreads();
  if (tid == 0) {
    float sgl = 0.0f;
    #pragma unroll
    for (int i = 0; i < 16; ++i) sgl += redB[i];
    scalars[2] = -2.0f * sgl;            // logdet(M)
  }
}

__device__ void gemm_body(GemmSh& sh, const float* __restrict__ x,
                          const unsigned short* __restrict__ VbT,
                          unsigned short* __restrict__ Yb, int blk) {
  auto& Xs = sh.Xs;
  auto& Vs = sh.Vs;
  int tid = threadIdx.x;                 // < 512
  int row0 = blk * GBM;
  int wid = tid >> 6, lane = tid & 63;
  int lr = lane & 15, lk = (lane >> 4) * 8;
  int rt = wid & 1;
  int cg = wid >> 1;
  int ct0 = (cg == 0) ? 0 : (cg * 2 + 1);
  int nct = (cg == 0) ? 3 : 2;

  int sxr = tid >> 4;
  int sxk = (tid & 15) * 8;
  int vrb = tid >> 4;
  int vk  = (tid & 15) * 8;

  float4 xr0, xr1;
  uint4 vr0, vr1, vr2, vr3, vr4;
  {
    const float* xb = &x[(size_t)(row0 + sxr) * D + sxk];
    xr0 = *reinterpret_cast<const float4*>(xb);
    xr1 = *reinterpret_cast<const float4*>(xb + 4);
    const unsigned short* vb = &VbT[(size_t)vrb * D + vk];
    vr0 = *reinterpret_cast<const uint4*>(vb);
    vr1 = *reinterpret_cast<const uint4*>(vb + (size_t)32 * D);
    vr2 = *reinterpret_cast<const uint4*>(vb + (size_t)64 * D);
    vr3 = *reinterpret_cast<const uint4*>(vb + (size_t)96 * D);
    if (tid < 256) vr4 = *reinterpret_cast<const uint4*>(vb + (size_t)128 * D);
  }

  f32x4 acc0 = {0, 0, 0, 0}, acc1 = {0, 0, 0, 0}, acc2 = {0, 0, 0, 0};

  for (int s = 0; s < NSTEP; ++s) {
    {
      uint4 w;
      w.x = (unsigned)f2bf(xr0.x) | ((unsigned)f2bf(xr0.y) << 16);
      w.y = (unsigned)f2bf(xr0.z) | ((unsigned)f2bf(xr0.w) << 16);
      w.z = (unsigned)f2bf(xr1.x) | ((unsigned)f2bf(xr1.y) << 16);
      w.w = (unsigned)f2bf(xr1.z) | ((unsigned)f2bf(xr1.w) << 16);
      *reinterpret_cast<uint4*>(&Xs[sxr][sxk]) = w;
      unsigned short* vd = &Vs[vrb][vk];
      *reinterpret_cast<uint4*>(vd) = vr0;
      *reinterpret_cast<uint4*>(vd + 32 * XSS) = vr1;
      *reinterpret_cast<uint4*>(vd + 64 * XSS) = vr2;
      *reinterpret_cast<uint4*>(vd + 96 * XSS) = vr3;
      if (tid < 256) *reinterpret_cast<uint4*>(vd + 128 * XSS) = vr4;
    }
    __syncthreads();
    if (s + 1 < NSTEP) {
      const float* xb = &x[(size_t)(row0 + sxr) * D + (s + 1) * GBK + sxk];
      xr0 = *reinterpret_cast<const float4*>(xb);
      xr1 = *reinterpret_cast<const float4*>(xb + 4);
      const unsigned short* vb = &VbT[(size_t)vrb * D + (s + 1) * GBK + vk];
      vr0 = *reinterpret_cast<const uint4*>(vb);
      vr1 = *reinterpret_cast<const uint4*>(vb + (size_t)32 * D);
      vr2 = *reinterpret_cast<const uint4*>(vb + (size_t)64 * D);
      vr3 = *reinterpret_cast<const uint4*>(vb + (size_t)96 * D);
      if (tid < 256) vr4 = *reinterpret_cast<const uint4*>(vb + (size_t)128 * D);
    }
    #pragma unroll
    for (int ks = 0; ks < 4; ++ks) {
      bh8 a = *reinterpret_cast<const bh8*>(&Xs[rt * 16 + lr][ks * 32 + lk]);
      bh8 b0 = *reinterpret_cast<const bh8*>(&Vs[ct0 * 16 + lr][ks * 32 + lk]);
      acc0 = __builtin_amdgcn_mfma_f32_16x16x32_bf16(a, b0, acc0, 0, 0, 0);
      bh8 b1 = *reinterpret_cast<const bh8*>(&Vs[(ct0 + 1) * 16 + lr][ks * 32 + lk]);
      acc1 = __builtin_amdgcn_mfma_f32_16x16x32_bf16(a, b1, acc1, 0, 0, 0);
      if (nct == 3) {
        bh8 b2 = *reinterpret_cast<const bh8*>(&Vs[(ct0 + 2) * 16 + lr][ks * 32 + lk]);
        acc2 = __builtin_amdgcn_mfma_f32_16x16x32_bf16(a, b2, acc2, 0, 0, 0);
      }
    }
    __syncthreads();
  }

  int rw = row0 + rt * 16 + ((lane >> 4) << 2);
  #pragma unroll
  for (int g = 0; g < 4; ++g)
    Yb[(size_t)(rw + g) * NC + ct0 * 16 + lr] = f2bf(acc0[g]);
  #pragma unroll
  for (int g = 0; g < 4; ++g)
    Yb[(size_t)(rw + g) * NC + (ct0 + 1) * 16 + lr] = f2bf(acc1[g]);
  if (nct == 3) {
    #pragma unroll
    for (int g = 0; g < 4; ++g)
      Yb[(size_t)(rw + g) * NC + (ct0 + 2) * 16 + lr] = f2bf(acc2[g]);
  }
}

__device__ void colstats_body(const float* __restrict__ x,
                              float* __restrict__ colsum,
                              float* __restrict__ colsumsq, int cb) {
  int d4 = threadIdx.x;                  // 0..1023 covers D/4
  int i0 = cb * CS_ROWS;
  float4 s1 = {0, 0, 0, 0}, s2 = {0, 0, 0, 0};
  for (int i = i0; i < i0 + CS_ROWS; ++i) {
    float4 v = *reinterpret_cast<const float4*>(&x[(size_t)i * D + d4 * 4]);
    s1.x += v.x; s1.y += v.y; s1.z += v.z; s1.w += v.w;
    s2.x += v.x * v.x; s2.y += v.y * v.y; s2.z += v.z * v.z; s2.w += v.w * v.w;
  }
  atomicAdd(&colsum[d4 * 4 + 0], s1.x); atomicAdd(&colsum[d4 * 4 + 1], s1.y);
  atomicAdd(&colsum[d4 * 4 + 2], s1.z); atomicAdd(&colsum[d4 * 4 + 3], s1.w);
  atomicAdd(&colsumsq[d4 * 4 + 0], s2.x); atomicAdd(&colsumsq[d4 * 4 + 1], s2.y);
  atomicAdd(&colsumsq[d4 * 4 + 2], s2.z); atomicAdd(&colsumsq[d4 * 4 + 3], s2.w);
}

__global__ __launch_bounds__(1024, 1) void k_par(const float* __restrict__ x,
                                                 const unsigned short* __restrict__ VbT,
                                                 unsigned short* __restrict__ Yb,
                                                 const float* __restrict__ Mg,
                                                 float* __restrict__ Gg,
                                                 float* __restrict__ scalars,
                                                 float* __restrict__ colsum,
                                                 float* __restrict__ colsumsq) {
  __shared__ ParSh sh;
  int b = blockIdx.x;
  if (b == 0) {
    chol_body(sh.c, Mg, Gg, scalars);
  } else if (b <= GEMM_BLOCKS) {
    if (threadIdx.x >= 512) return;      // exit before any barrier
    gemm_body(sh.g, x, VbT, Yb, b - 1);
  } else {
    colstats_body(x, colsum, colsumsq, b - 1 - GEMM_BLOCKS);
  }
}

// ---------------- Q += Yb^T Yb  (bf16 in, symmetry, row-split atomics) ----------------
#define SYRK_ZSPLIT 16
__global__ __launch_bounds__(256) void k_syrk(const unsigned short* __restrict__ Yb,
                                              float* __restrict__ Q) {
  int bj = blockIdx.x * 16, bk = blockIdx.y * 16;
  if (bk < bj) return;                   // symmetry
  __shared__ float Ya[64][17];
  __shared__ float Yc[64][17];
  int i0base = blockIdx.z * (NROWS / SYRK_ZSPLIT);
  int tid = threadIdx.x;
  int tj = tid & 15, tk = tid >> 4;
  int lr = tid >> 2, lc = (tid & 3) * 4;
  float acc = 0.0f;
  for (int i0 = i0base; i0 < i0base + NROWS / SYRK_ZSPLIT; i0 += 64) {
    ushort4 va = *reinterpret_cast<const ushort4*>(&Yb[(size_t)(i0 + lr) * NC + bj + lc]);
    ushort4 vc = *reinterpret_cast<const ushort4*>(&Yb[(size_t)(i0 + lr) * NC + bk + lc]);
    Ya[lr][lc + 0] = bf2f(va.x); Ya[lr][lc + 1] = bf2f(va.y);
    Ya[lr][lc + 2] = bf2f(va.z); Ya[lr][lc + 3] = bf2f(va.w);
    Yc[lr][lc + 0] = bf2f(vc.x); Yc[lr][lc + 1] = bf2f(vc.y);
    Yc[lr][lc + 2] = bf2f(vc.z); Yc[lr][lc + 3] = bf2f(vc.w);
    __syncthreads();
    #pragma unroll
    for (int ii = 0; ii < 64; ++ii) acc += Ya[ii][tj] * Yc[ii][tk];
    __syncthreads();
  }
  atomicAdd(&Q[(bj + tj) * QS + bk + tk], acc);
  if (bj != bk) atomicAdd(&Q[(bk + tk) * QS + bj + tj], acc);
}

// ---------------- k_trace: tr(M^-1 S) = sum_{j<=k} (2-d) H_jk S_jk, H = G^T G ----------------
__global__ __launch_bounds__(256) void k_trace(const float* __restrict__ Gg,
                                               const float* __restrict__ Qg,
                                               const float* __restrict__ tvec,
                                               const float* __restrict__ mvec,
                                               float* __restrict__ scalars) {
  int bj = blockIdx.x * 16, bk = blockIdx.y * 16;
  if (bk < bj) return;                   // upper tiles only
  int tj = threadIdx.x & 15, tk = threadIdx.x >> 4;
  int j = bj + tj, k = bk + tk;
  float acc = 0.0f;
  if (j <= k && k < NP) {
    float h0 = 0.f, h1 = 0.f;
    int i = k;
    for (; i + 1 < NP; i += 2) {
      h0 += Gg[(size_t)i * NP + j] * Gg[(size_t)i * NP + k];
      h1 += Gg[(size_t)(i + 1) * NP + j] * Gg[(size_t)(i + 1) * NP + k];
    }
    for (; i < NP; ++i) h0 += Gg[(size_t)i * NP + j] * Gg[(size_t)i * NP + k];
    float h = h0 + h1;
    float S = 0.0f;
    if (j < KP && k < KP) {
      float tlj = tvec[j], mlj = mvec[j], tlk = tvec[k], mlk = mvec[k];
      S = Qg[j * QS + k] - tlj * mlk - mlj * tlk + (float)NROWS * mlj * mlk;
    }
    acc = ((j == k) ? 1.0f : 2.0f) * h * S;
  }
  float r = blockReduceSum256(acc);
  if (threadIdx.x == 0) atomicAdd(&scalars[3], r);
}

// ---------------- k_combine ----------------
__global__ void k_combine(const float* __restrict__ scalars,
                          const int* __restrict__ fds,
                          float* __restrict__ out) {
  if (threadIdx.x == 0) {
    double sumlog  = (double)scalars[0];
    double term1   = (double)scalars[1];
    double logdetM = (double)scalars[2];
    double tr      = (double)scalars[3];
    double total = (double)NROWS * (double)D * LOG2PI
                 + (double)NROWS * (sumlog + logdetM)
                 + term1 - tr;
    double scale = (double)fds[0] / (double)NROWS;
    out[0] = (float)(scale * (-0.5) * total);
  }
}

// ---------------- launch ----------------
extern "C" void kernel_launch(void* const* d_in, const int* in_sizes, int n_in,
                              void* d_out, int out_size, void* d_ws, size_t ws_size,
                              hipStream_t stream) {
  const float* x     = (const float*)d_in[0];
  const float* theta = (const float*)d_in[1];
  const int*   fds   = (const int*)d_in[2];
  float* out = (float*)d_out;
  char* ws = (char*)d_ws;

  unsigned short* Yb  = (unsigned short*)ws;                       // 8192*144*2 = 2359296
  unsigned short* VbT = (unsigned short*)(ws + 2359296);           // 144*4096*2 = 1179648
  float* Q        = (float*)(ws + 2359296 + 1179648);              // QS*QS*4 = 82944
  float* colsum   = (float*)(ws + 2359296 + 1179648 + 82944);      // D*4
  float* colsumsq = colsum + D;                                    // D*4
  float* M        = colsumsq + D;                                  // KP*MS*4
  float* tvec     = M + KP * MS;
  float* mvec     = tvec + MS;
  float* scalars  = mvec + MS;                                     // 8 floats
  float* Gg       = scalars + 8;                                   // NP*NP = 17424

  // zero atomic accumulators: Q + colsum + colsumsq (contiguous)
  hipMemsetAsync(Q, 0, (size_t)(QS * QS + 2 * D) * sizeof(float), stream);

  k_prep   <<<dim3(NC), 256, 0, stream>>>(theta, VbT);
  k_M      <<<dim3(KP, KP), 256, 0, stream>>>(theta, VbT, M);
  k_par    <<<dim3(1 + GEMM_BLOCKS + CS_BLOCKS), 1024, 0, stream>>>(
               x, VbT, Yb, M, Gg, scalars, colsum, colsumsq);
  k_syrk   <<<dim3(QS / 16, QS / 16, SYRK_ZSPLIT), 256, 0, stream>>>(Yb, Q);
  k_small  <<<dim3(2 * KP + 1), 256, 0, stream>>>(theta, VbT, colsum, colsumsq,
                                                  tvec, mvec, scalars);
  k_trace  <<<dim3(9, 9), 256, 0, stream>>>(Gg, Q, tvec, mvec, scalars);
  k_combine<<<dim3(1), 64, 0, stream>>>(scalars, fds, out);
}